// Round 4
// baseline (4253.205 us; speedup 1.0000x reference)
//
#include <hip/hip_runtime.h>
#include <hip/hip_bf16.h>

typedef __hip_bfloat16 bf16;

#define Bq   2
#define Tq   2048
#define Dq   2048
#define NHq  16
#define HDq  48
#define LATq 256
#define NLHq 8
#define QN   (NHq * HDq)    // 768
#define KVN  (NLHq * HDq)   // 384

__device__ __forceinline__ float b2f(bf16 v) { return __bfloat162float(v); }

// ------------- q = x @ Wq : [4096,2048] x [2048,768] -> fp32, 4 rows/block ------
// q is stored in d_out (fp32): dead before mla_oproj overwrites d_out.
extern "C" __global__ void __launch_bounds__(256)
mla_qproj(const float* __restrict__ x, const float* __restrict__ Wq, float* __restrict__ q) {
    __shared__ float xs[4][Dq];              // 32 KB
    const int r0 = blockIdx.x * 4;
    for (int idx = threadIdx.x; idx < 4 * Dq; idx += 256) {
        const int r = idx >> 11, k = idx & (Dq - 1);
        xs[r][k] = x[(size_t)(r0 + r) * Dq + k];
    }
    __syncthreads();
    const int t = threadIdx.x;
    float acc[4][3];
    #pragma unroll
    for (int r = 0; r < 4; ++r)
        #pragma unroll
        for (int c = 0; c < 3; ++c) acc[r][c] = 0.f;
    for (int k = 0; k < Dq; ++k) {
        const float* wr = Wq + (size_t)k * QN;
        const float w0 = wr[t], w1 = wr[t + 256], w2 = wr[t + 512];
        #pragma unroll
        for (int r = 0; r < 4; ++r) {
            const float xv = xs[r][k];       // LDS broadcast
            acc[r][0] = fmaf(xv, w0, acc[r][0]);
            acc[r][1] = fmaf(xv, w1, acc[r][1]);
            acc[r][2] = fmaf(xv, w2, acc[r][2]);
        }
    }
    #pragma unroll
    for (int r = 0; r < 4; ++r) {
        float* qr = q + (size_t)(r0 + r) * QN;
        qr[t] = acc[r][0]; qr[t + 256] = acc[r][1]; qr[t + 512] = acc[r][2];
    }
}

// ------------- lat = rmsnorm(x @ Wkv) : [4096,2048] x [2048,256] -> fp32 -------
extern "C" __global__ void __launch_bounds__(256)
mla_kvlat(const float* __restrict__ x, const float* __restrict__ Wkv,
          const float* __restrict__ wn, float* __restrict__ lat) {
    __shared__ float xs[Dq];
    __shared__ float red[256];
    const int row = blockIdx.x;
    const float* xr = x + (size_t)row * Dq;
    for (int k = threadIdx.x; k < Dq; k += 256) xs[k] = xr[k];
    __syncthreads();
    const int t = threadIdx.x;
    float acc = 0.f;
    for (int k = 0; k < Dq; ++k)
        acc = fmaf(xs[k], Wkv[(size_t)k * LATq + t], acc);
    red[t] = acc * acc;
    __syncthreads();
    for (int s = 128; s > 0; s >>= 1) {
        if (t < s) red[t] += red[t + s];
        __syncthreads();
    }
    const float r = rsqrtf(red[0] * (1.0f / LATq) + 1e-5f);
    lat[(size_t)row * LATq + t] = acc * r * wn[t];
}

// ------- k,v = lat @ Wk / lat @ Wv : [4096,256] x [256,384] -> bf16 ------------
extern "C" __global__ void __launch_bounds__(384)
mla_kvproj(const float* __restrict__ lat, const float* __restrict__ Wk,
           const float* __restrict__ Wv, bf16* __restrict__ ko, bf16* __restrict__ vo) {
    __shared__ float ls[LATq];
    const int row = blockIdx.x;
    const int t = threadIdx.x;                // 0..383
    if (t < LATq) ls[t] = lat[(size_t)row * LATq + t];
    __syncthreads();
    float ak = 0.f, av = 0.f;
    for (int k = 0; k < LATq; ++k) {
        const float lv = ls[k];
        ak = fmaf(lv, Wk[(size_t)k * KVN + t], ak);
        av = fmaf(lv, Wv[(size_t)k * KVN + t], av);
    }
    ko[(size_t)row * KVN + t] = __float2bfloat16(ak);
    vo[(size_t)row * KVN + t] = __float2bfloat16(av);
}

// --------- causal online-softmax attention, one wave per (b,h,i) ---------------
extern "C" __global__ void __launch_bounds__(64)
mla_attn(const float* __restrict__ q, const bf16* __restrict__ kk,
         const bf16* __restrict__ vv, float* __restrict__ ao) {
    const int i = blockIdx.x;
    const int h = blockIdx.y;
    const int b = blockIdx.z;
    const int g = h >> 1;                     // jnp.repeat(.., 2, axis=2): head h -> latent head h/2
    const int lane = threadIdx.x;
    const float scale = 0.14433756729740643f; // 1/sqrt(48)

    float qv[HDq];
    const float* qr = q + (size_t)(b * Tq + i) * QN + h * HDq;
    #pragma unroll
    for (int d = 0; d < HDq; ++d) qv[d] = qr[d] * scale;

    float m = -1e30f, l = 0.f;
    float acc[HDq];
    #pragma unroll
    for (int d = 0; d < HDq; ++d) acc[d] = 0.f;

    const bf16* kb = kk + (size_t)b * Tq * KVN + g * HDq;
    const bf16* vb = vv + (size_t)b * Tq * KVN + g * HDq;

    for (int j0 = 0; j0 <= i; j0 += 64) {
        const int j = j0 + lane;
        if (j <= i) {
            const bf16* kr = kb + (size_t)j * KVN;
            float s = 0.f;
            #pragma unroll
            for (int d = 0; d < HDq; ++d) s = fmaf(qv[d], b2f(kr[d]), s);
            const float nm = fmaxf(m, s);
            const float f = __expf(m - nm);
            const float p = __expf(s - nm);
            l = l * f + p;
            const bf16* vr = vb + (size_t)j * KVN;
            #pragma unroll
            for (int d = 0; d < HDq; ++d) acc[d] = fmaf(acc[d], f, p * b2f(vr[d]));
            m = nm;
        }
    }
    // cross-lane combine: lanes that saw no j have m=-1e30 -> exp underflows to 0
    float M = m;
    #pragma unroll
    for (int o = 32; o > 0; o >>= 1) M = fmaxf(M, __shfl_xor(M, o));
    const float fac = __expf(m - M);
    float L = l * fac;
    #pragma unroll
    for (int o = 32; o > 0; o >>= 1) L += __shfl_xor(L, o);
    const float inv = 1.0f / L;
    #pragma unroll
    for (int d = 0; d < HDq; ++d) {
        float a = acc[d] * fac;
        #pragma unroll
        for (int o = 32; o > 0; o >>= 1) a += __shfl_xor(a, o);
        acc[d] = a * inv;                     // every lane now holds the final value
    }
    if (lane == 0) {
        float* orow = ao + (size_t)(b * Tq + i) * QN + h * HDq;
        #pragma unroll
        for (int d = 0; d < HDq; ++d) orow[d] = acc[d];
    }
}

// ---------- out = ao @ Wo : [4096,768] x [768,2048] -> fp32, 4 rows/block -------
extern "C" __global__ void __launch_bounds__(256)
mla_oproj(const float* __restrict__ ao, const float* __restrict__ Wo, float* __restrict__ out) {
    __shared__ float as[4][QN];               // 12 KB
    const int r0 = blockIdx.x * 4;
    for (int idx = threadIdx.x; idx < 4 * QN; idx += 256) {
        const int r = idx / QN, k = idx - r * QN;
        as[r][k] = ao[(size_t)(r0 + r) * QN + k];
    }
    __syncthreads();
    const int t = threadIdx.x;
    float acc[4][8];
    #pragma unroll
    for (int r = 0; r < 4; ++r)
        #pragma unroll
        for (int c = 0; c < 8; ++c) acc[r][c] = 0.f;
    for (int k = 0; k < QN; ++k) {
        const float* wr = Wo + (size_t)k * Dq;
        float w[8];
        #pragma unroll
        for (int c = 0; c < 8; ++c) w[c] = wr[t + 256 * c];
        #pragma unroll
        for (int r = 0; r < 4; ++r) {
            const float a = as[r][k];
            #pragma unroll
            for (int c = 0; c < 8; ++c) acc[r][c] = fmaf(a, w[c], acc[r][c]);
        }
    }
    #pragma unroll
    for (int r = 0; r < 4; ++r) {
        float* orow = out + (size_t)(r0 + r) * Dq;
        #pragma unroll
        for (int c = 0; c < 8; ++c) orow[t + 256 * c] = acc[r][c];
    }
}

extern "C" void kernel_launch(void* const* d_in, const int* in_sizes, int n_in,
                              void* d_out, int out_size, void* d_ws, size_t ws_size,
                              hipStream_t stream) {
    const float* x   = (const float*)d_in[0];
    // d_in[1]: causal mask — static tril, applied analytically in mla_attn
    const float* Wq  = (const float*)d_in[2];
    const float* Wkv = (const float*)d_in[3];
    const float* wn  = (const float*)d_in[4];
    const float* Wk  = (const float*)d_in[5];
    const float* Wv  = (const float*)d_in[6];
    const float* Wo  = (const float*)d_in[7];
    float* out = (float*)d_out;

    const int M = Bq * Tq;                          // 4096 rows
    // q lives in d_out (3.1M fp32 of its 8.4M): dead before mla_oproj overwrites.
    float* qws = out;
    // ws layout: lat fp32 4.2MB | k bf16 3.15MB | v bf16 3.15MB | ao fp32 12.6MB = 23.1MB
    float* lat = (float*)d_ws;
    bf16*  kws = (bf16*)(lat + (size_t)M * LATq);
    bf16*  vws = kws + (size_t)M * KVN;
    float* aob = (float*)(vws + (size_t)M * KVN);

    mla_qproj <<<M / 4, 256, 0, stream>>>(x, Wq, qws);
    mla_kvlat <<<M, 256, 0, stream>>>(x, Wkv, wn, lat);
    mla_kvproj<<<M, 384, 0, stream>>>(lat, Wk, Wv, kws, vws);
    mla_attn  <<<dim3(Tq, NHq, Bq), 64, 0, stream>>>(qws, kws, vws, aob);
    mla_oproj <<<M / 4, 256, 0, stream>>>(aob, Wo, out);
}

// Round 5
// 1835.906 us; speedup vs baseline: 2.3167x; 2.3167x over previous
//
#include <hip/hip_runtime.h>
#include <hip/hip_bf16.h>

typedef __hip_bfloat16 bf16;

#define Bq   2
#define Tq   2048
#define Dq   2048
#define NHq  16
#define HDq  48
#define LATq 256
#define NLHq 8
#define QN   (NHq * HDq)    // 768
#define KVN  (NLHq * HDq)   // 384
#define KPAD 52             // LDS row stride (floats): 16B-aligned, odd/32 mix kills conflicts

__device__ __forceinline__ float b2f(bf16 v) { return __bfloat162float(v); }

// ---- q = x @ Wq : [4096,2048]x[2048,768] -> bf16 (into d_out), 8 rows/block ----
extern "C" __global__ void __launch_bounds__(256)
mla_qproj(const float* __restrict__ x, const float* __restrict__ Wq, bf16* __restrict__ q) {
    __shared__ float xs[8][1024];            // 32 KB, k-chunked
    const int r0 = blockIdx.x * 8;
    const int t = threadIdx.x;
    float acc[8][3];
    #pragma unroll
    for (int r = 0; r < 8; ++r)
        #pragma unroll
        for (int c = 0; c < 3; ++c) acc[r][c] = 0.f;

    for (int kc = 0; kc < 2; ++kc) {
        __syncthreads();
        // stage 8 rows x 1024 cols (2048 float4, 8 per thread)
        #pragma unroll
        for (int n = 0; n < 8; ++n) {
            const int idx4 = t + 256 * n;
            const int r = idx4 >> 8, c4 = idx4 & 255;
            *(float4*)&xs[r][c4 * 4] =
                *(const float4*)&x[(size_t)(r0 + r) * Dq + kc * 1024 + c4 * 4];
        }
        __syncthreads();
        for (int k = 0; k < 1024; ++k) {
            const float* wr = Wq + (size_t)(kc * 1024 + k) * QN;
            const float w0 = wr[t], w1 = wr[t + 256], w2 = wr[t + 512];
            #pragma unroll
            for (int r = 0; r < 8; ++r) {
                const float xv = xs[r][k];
                acc[r][0] = fmaf(xv, w0, acc[r][0]);
                acc[r][1] = fmaf(xv, w1, acc[r][1]);
                acc[r][2] = fmaf(xv, w2, acc[r][2]);
            }
        }
    }
    #pragma unroll
    for (int r = 0; r < 8; ++r) {
        bf16* qr = q + (size_t)(r0 + r) * QN;
        qr[t]       = __float2bfloat16(acc[r][0]);
        qr[t + 256] = __float2bfloat16(acc[r][1]);
        qr[t + 512] = __float2bfloat16(acc[r][2]);
    }
}

// ---- lat = rmsnorm(x @ Wkv) : [4096,2048]x[2048,256] -> fp32, 4 rows/block ----
extern "C" __global__ void __launch_bounds__(256)
mla_kvlat(const float* __restrict__ x, const float* __restrict__ Wkv,
          const float* __restrict__ wn, float* __restrict__ lat) {
    __shared__ float xs[4][Dq];              // 32 KB
    __shared__ float red[4][256];            // 4 KB
    const int r0 = blockIdx.x * 4;
    const int t = threadIdx.x;
    #pragma unroll
    for (int n = 0; n < 8; ++n) {
        const int idx4 = t + 256 * n;
        const int r = idx4 >> 9, c4 = idx4 & 511;
        *(float4*)&xs[r][c4 * 4] = *(const float4*)&x[(size_t)(r0 + r) * Dq + c4 * 4];
    }
    __syncthreads();
    float acc[4] = {0.f, 0.f, 0.f, 0.f};
    for (int k = 0; k < Dq; ++k) {
        const float w = Wkv[(size_t)k * LATq + t];
        #pragma unroll
        for (int r = 0; r < 4; ++r) acc[r] = fmaf(xs[r][k], w, acc[r]);
    }
    #pragma unroll
    for (int r = 0; r < 4; ++r) red[r][t] = acc[r] * acc[r];
    __syncthreads();
    for (int s = 128; s > 0; s >>= 1) {
        if (t < s) {
            #pragma unroll
            for (int r = 0; r < 4; ++r) red[r][t] += red[r][t + s];
        }
        __syncthreads();
    }
    const float w = wn[t];
    #pragma unroll
    for (int r = 0; r < 4; ++r) {
        const float rr = rsqrtf(red[r][0] * (1.0f / LATq) + 1e-5f);
        lat[(size_t)(r0 + r) * LATq + t] = acc[r] * rr * w;
    }
}

// ------- k,v = lat @ Wk / lat @ Wv : [4096,256]x[256,384] -> fp32 --------------
extern "C" __global__ void __launch_bounds__(384)
mla_kvproj(const float* __restrict__ lat, const float* __restrict__ Wk,
           const float* __restrict__ Wv, float* __restrict__ ko, float* __restrict__ vo) {
    __shared__ float ls[LATq];
    const int row = blockIdx.x;
    const int t = threadIdx.x;                // 0..383
    if (t < LATq) ls[t] = lat[(size_t)row * LATq + t];
    __syncthreads();
    float ak = 0.f, av = 0.f;
    for (int k = 0; k < LATq; ++k) {
        const float lv = ls[k];
        ak = fmaf(lv, Wk[(size_t)k * KVN + t], ak);
        av = fmaf(lv, Wv[(size_t)k * KVN + t], av);
    }
    ko[(size_t)row * KVN + t] = ak;
    vo[(size_t)row * KVN + t] = av;
}

// ---- flash attention: block = 64 queries x 2 heads (one latent head g) --------
// K/V tiles (64 keys) staged in LDS fp32, shared by both heads and all queries.
extern "C" __global__ void __launch_bounds__(128)
mla_attn(const bf16* __restrict__ q, const float* __restrict__ kk,
         const float* __restrict__ vv, bf16* __restrict__ ao) {
    __shared__ float ks[64][KPAD];            // 13.3 KB
    __shared__ float vs[64][KPAD];            // 13.3 KB
    const int qt = (int)gridDim.x - 1 - (int)blockIdx.x;  // heavy tiles first (LPT)
    const int g  = blockIdx.y;
    const int b  = blockIdx.z;
    const int t  = threadIdx.x;               // 0..127
    const int lq = t & 63;                    // query within tile
    const int hh = t >> 6;                    // head within latent group
    const int i  = qt * 64 + lq;
    const int h  = g * 2 + hh;
    const float scale = 0.14433756729740643f; // 1/sqrt(48)

    float qv[HDq];
    const bf16* qr = q + (size_t)(b * Tq + i) * QN + h * HDq;
    #pragma unroll
    for (int d = 0; d < HDq; ++d) qv[d] = b2f(qr[d]) * scale;

    float m = -1e30f, l = 0.f;
    float acc[HDq];
    #pragma unroll
    for (int d = 0; d < HDq; ++d) acc[d] = 0.f;

    const float* kbase = kk + (size_t)b * Tq * KVN + g * HDq;
    const float* vbase = vv + (size_t)b * Tq * KVN + g * HDq;
    const int imin = qt * 64;
    const int jmax = qt * 64 + 63;

    for (int j0 = 0; j0 <= jmax; j0 += 64) {
        // stage: threads 0..63 -> K rows, 64..127 -> V rows (row j0+r always < Tq)
        {
            const int r = t & 63;
            const float* src = (t < 64) ? (kbase + (size_t)(j0 + r) * KVN)
                                        : (vbase + (size_t)(j0 + r) * KVN);
            float* dst = (t < 64) ? &ks[r][0] : &vs[r][0];
            #pragma unroll
            for (int c = 0; c < 12; ++c) {
                const float4 v4 = *(const float4*)(src + 4 * c);
                dst[4 * c + 0] = v4.x; dst[4 * c + 1] = v4.y;
                dst[4 * c + 2] = v4.z; dst[4 * c + 3] = v4.w;
            }
        }
        __syncthreads();

        const int jfullr = imin - j0 + 1;
        const int jfull = jfullr < 0 ? 0 : (jfullr > 64 ? 64 : jfullr);
        const int jendr = jmax - j0 + 1;
        const int jend  = jendr > 64 ? 64 : jendr;

        for (int jj = 0; jj < jfull; ++jj) {   // no causal guard needed
            const float4* kr = (const float4*)&ks[jj][0];
            float s0 = 0.f, s1 = 0.f, s2 = 0.f, s3 = 0.f;
            #pragma unroll
            for (int c = 0; c < 12; ++c) {
                const float4 k4 = kr[c];
                s0 = fmaf(qv[4 * c + 0], k4.x, s0);
                s1 = fmaf(qv[4 * c + 1], k4.y, s1);
                s2 = fmaf(qv[4 * c + 2], k4.z, s2);
                s3 = fmaf(qv[4 * c + 3], k4.w, s3);
            }
            const float s = (s0 + s1) + (s2 + s3);
            const float nm = fmaxf(m, s);
            const float f = __expf(m - nm);
            const float p = __expf(s - nm);
            l = l * f + p;
            const float4* vr = (const float4*)&vs[jj][0];
            #pragma unroll
            for (int c = 0; c < 12; ++c) {
                const float4 v4 = vr[c];
                acc[4 * c + 0] = fmaf(acc[4 * c + 0], f, p * v4.x);
                acc[4 * c + 1] = fmaf(acc[4 * c + 1], f, p * v4.y);
                acc[4 * c + 2] = fmaf(acc[4 * c + 2], f, p * v4.z);
                acc[4 * c + 3] = fmaf(acc[4 * c + 3], f, p * v4.w);
            }
            m = nm;
        }
        for (int jj = jfull; jj < jend; ++jj) { // causal boundary tile
            if (j0 + jj <= i) {
                const float4* kr = (const float4*)&ks[jj][0];
                float s0 = 0.f, s1 = 0.f, s2 = 0.f, s3 = 0.f;
                #pragma unroll
                for (int c = 0; c < 12; ++c) {
                    const float4 k4 = kr[c];
                    s0 = fmaf(qv[4 * c + 0], k4.x, s0);
                    s1 = fmaf(qv[4 * c + 1], k4.y, s1);
                    s2 = fmaf(qv[4 * c + 2], k4.z, s2);
                    s3 = fmaf(qv[4 * c + 3], k4.w, s3);
                }
                const float s = (s0 + s1) + (s2 + s3);
                const float nm = fmaxf(m, s);
                const float f = __expf(m - nm);
                const float p = __expf(s - nm);
                l = l * f + p;
                const float4* vr = (const float4*)&vs[jj][0];
                #pragma unroll
                for (int c = 0; c < 12; ++c) {
                    const float4 v4 = vr[c];
                    acc[4 * c + 0] = fmaf(acc[4 * c + 0], f, p * v4.x);
                    acc[4 * c + 1] = fmaf(acc[4 * c + 1], f, p * v4.y);
                    acc[4 * c + 2] = fmaf(acc[4 * c + 2], f, p * v4.z);
                    acc[4 * c + 3] = fmaf(acc[4 * c + 3], f, p * v4.w);
                }
                m = nm;
            }
        }
        __syncthreads();
    }
    const float inv = 1.0f / l;
    bf16* orow = ao + (size_t)(b * Tq + i) * QN + h * HDq;
    #pragma unroll
    for (int d = 0; d < HDq; ++d) orow[d] = __float2bfloat16(acc[d] * inv);
}

// ---- out = ao(bf16) @ Wo : [4096,768]x[768,2048] -> fp32, 8 rows/block --------
extern "C" __global__ void __launch_bounds__(256)
mla_oproj(const bf16* __restrict__ ao, const float* __restrict__ Wo, float* __restrict__ out) {
    __shared__ float as[8][QN];               // 24 KB
    const int r0 = blockIdx.x * 8;
    const int t = threadIdx.x;
    #pragma unroll
    for (int r = 0; r < 8; ++r)
        for (int c = t; c < QN; c += 256)
            as[r][c] = b2f(ao[(size_t)(r0 + r) * QN + c]);
    __syncthreads();
    float acc[8][8];
    #pragma unroll
    for (int r = 0; r < 8; ++r)
        #pragma unroll
        for (int c = 0; c < 8; ++c) acc[r][c] = 0.f;
    for (int k = 0; k < QN; ++k) {
        const float* wr = Wo + (size_t)k * Dq;
        float w[8];
        #pragma unroll
        for (int c = 0; c < 8; ++c) w[c] = wr[t + 256 * c];
        #pragma unroll
        for (int r = 0; r < 8; ++r) {
            const float a = as[r][k];
            #pragma unroll
            for (int c = 0; c < 8; ++c) acc[r][c] = fmaf(a, w[c], acc[r][c]);
        }
    }
    #pragma unroll
    for (int r = 0; r < 8; ++r) {
        float* orow = out + (size_t)(r0 + r) * Dq;
        #pragma unroll
        for (int c = 0; c < 8; ++c) orow[t + 256 * c] = acc[r][c];
    }
}

extern "C" void kernel_launch(void* const* d_in, const int* in_sizes, int n_in,
                              void* d_out, int out_size, void* d_ws, size_t ws_size,
                              hipStream_t stream) {
    const float* x   = (const float*)d_in[0];
    // d_in[1]: causal mask — static tril, applied analytically in mla_attn
    const float* Wq  = (const float*)d_in[2];
    const float* Wkv = (const float*)d_in[3];
    const float* wn  = (const float*)d_in[4];
    const float* Wk  = (const float*)d_in[5];
    const float* Wv  = (const float*)d_in[6];
    const float* Wo  = (const float*)d_in[7];
    float* out = (float*)d_out;

    const int M = Bq * Tq;                          // 4096 rows
    // q bf16 parked in d_out (6.29 MB of 16.8 MB): dead before mla_oproj overwrites.
    bf16* qws = (bf16*)d_out;
    // ws: lat fp32 4.19MB | k fp32 6.29MB | v fp32 6.29MB | ao bf16 6.29MB = 23.07MB (== R4 proven)
    float* lat = (float*)d_ws;
    float* kws = lat + (size_t)M * LATq;
    float* vws = kws + (size_t)M * KVN;
    bf16*  aob = (bf16*)(vws + (size_t)M * KVN);

    mla_qproj <<<M / 8, 256, 0, stream>>>(x, Wq, qws);
    mla_kvlat <<<M / 4, 256, 0, stream>>>(x, Wkv, wn, lat);
    mla_kvproj<<<M, 384, 0, stream>>>(lat, Wk, Wv, kws, vws);
    mla_attn  <<<dim3(Tq / 64, NLHq, Bq), 128, 0, stream>>>(qws, kws, vws, aob);
    mla_oproj <<<M / 8, 256, 0, stream>>>(aob, Wo, out);
}

// Round 6
// 1797.888 us; speedup vs baseline: 2.3657x; 1.0211x over previous
//
#include <hip/hip_runtime.h>
#include <hip/hip_bf16.h>

typedef __hip_bfloat16 bf16;

#define Bq   2
#define Tq   2048
#define Dq   2048
#define NHq  16
#define HDq  48
#define LATq 256
#define NLHq 8
#define QN   (NHq * HDq)    // 768
#define KVN  (NLHq * HDq)   // 384
#define KPAD 52             // LDS K/V row stride (floats): 16B-aligned

__device__ __forceinline__ float b2f(bf16 v) { return __bfloat162float(v); }

// ---- q = x @ Wq : [4096,2048]x[2048,768] -> bf16 (into d_out), 8 rows/block ----
extern "C" __global__ void __launch_bounds__(256)
mla_qproj(const float* __restrict__ x, const float* __restrict__ Wq, bf16* __restrict__ q) {
    __shared__ float xs[8][1024];            // 32 KB, k-chunked
    const int r0 = blockIdx.x * 8;
    const int t = threadIdx.x;
    float acc[8][3];
    #pragma unroll
    for (int r = 0; r < 8; ++r)
        #pragma unroll
        for (int c = 0; c < 3; ++c) acc[r][c] = 0.f;

    for (int kc = 0; kc < 2; ++kc) {
        __syncthreads();
        #pragma unroll
        for (int n = 0; n < 8; ++n) {
            const int idx4 = t + 256 * n;
            const int r = idx4 >> 8, c4 = idx4 & 255;
            *(float4*)&xs[r][c4 * 4] =
                *(const float4*)&x[(size_t)(r0 + r) * Dq + kc * 1024 + c4 * 4];
        }
        __syncthreads();
        for (int k = 0; k < 1024; ++k) {
            const float* wr = Wq + (size_t)(kc * 1024 + k) * QN;
            const float w0 = wr[t], w1 = wr[t + 256], w2 = wr[t + 512];
            #pragma unroll
            for (int r = 0; r < 8; ++r) {
                const float xv = xs[r][k];
                acc[r][0] = fmaf(xv, w0, acc[r][0]);
                acc[r][1] = fmaf(xv, w1, acc[r][1]);
                acc[r][2] = fmaf(xv, w2, acc[r][2]);
            }
        }
    }
    #pragma unroll
    for (int r = 0; r < 8; ++r) {
        bf16* qr = q + (size_t)(r0 + r) * QN;
        qr[t]       = __float2bfloat16(acc[r][0]);
        qr[t + 256] = __float2bfloat16(acc[r][1]);
        qr[t + 512] = __float2bfloat16(acc[r][2]);
    }
}

// ---- lat = rmsnorm(x @ Wkv) : [4096,2048]x[2048,256] -> fp32, 8 rows/block ----
extern "C" __global__ void __launch_bounds__(256)
mla_kvlat(const float* __restrict__ x, const float* __restrict__ Wkv,
          const float* __restrict__ wn, float* __restrict__ lat) {
    __shared__ float xs[8][1024];            // 32 KB, k-chunked
    __shared__ float red[8][256];            // 8 KB
    const int r0 = blockIdx.x * 8;
    const int t = threadIdx.x;
    float acc[8];
    #pragma unroll
    for (int r = 0; r < 8; ++r) acc[r] = 0.f;

    for (int kc = 0; kc < 2; ++kc) {
        __syncthreads();
        #pragma unroll
        for (int n = 0; n < 8; ++n) {
            const int idx4 = t + 256 * n;
            const int r = idx4 >> 8, c4 = idx4 & 255;
            *(float4*)&xs[r][c4 * 4] =
                *(const float4*)&x[(size_t)(r0 + r) * Dq + kc * 1024 + c4 * 4];
        }
        __syncthreads();
        for (int k = 0; k < 1024; ++k) {
            const float w = Wkv[(size_t)(kc * 1024 + k) * LATq + t];
            #pragma unroll
            for (int r = 0; r < 8; ++r) acc[r] = fmaf(xs[r][k], w, acc[r]);
        }
    }
    #pragma unroll
    for (int r = 0; r < 8; ++r) red[r][t] = acc[r] * acc[r];
    __syncthreads();
    for (int s = 128; s > 0; s >>= 1) {
        if (t < s) {
            #pragma unroll
            for (int r = 0; r < 8; ++r) red[r][t] += red[r][t + s];
        }
        __syncthreads();
    }
    const float w = wn[t];
    #pragma unroll
    for (int r = 0; r < 8; ++r) {
        const float rr = rsqrtf(red[r][0] * (1.0f / LATq) + 1e-5f);
        lat[(size_t)(r0 + r) * LATq + t] = acc[r] * rr * w;
    }
}

// ---- k,v = lat @ Wk / lat @ Wv : [4096,256]x[256,384] -> fp32, 8 rows/block ---
extern "C" __global__ void __launch_bounds__(384)
mla_kvproj(const float* __restrict__ lat, const float* __restrict__ Wk,
           const float* __restrict__ Wv, float* __restrict__ ko, float* __restrict__ vo) {
    __shared__ float ls[8][LATq];             // 8 KB
    const int r0 = blockIdx.x * 8;
    const int t = threadIdx.x;                // 0..383
    for (int idx = t; idx < 8 * LATq; idx += 384) {
        const int r = idx >> 8, c = idx & 255;
        ls[r][c] = lat[(size_t)(r0 + r) * LATq + c];
    }
    __syncthreads();
    float ak[8], av[8];
    #pragma unroll
    for (int r = 0; r < 8; ++r) { ak[r] = 0.f; av[r] = 0.f; }
    for (int k = 0; k < LATq; ++k) {
        const float wk = Wk[(size_t)k * KVN + t];
        const float wv = Wv[(size_t)k * KVN + t];
        #pragma unroll
        for (int r = 0; r < 8; ++r) {
            const float lv = ls[r][k];
            ak[r] = fmaf(lv, wk, ak[r]);
            av[r] = fmaf(lv, wv, av[r]);
        }
    }
    #pragma unroll
    for (int r = 0; r < 8; ++r) {
        ko[(size_t)(r0 + r) * KVN + t] = ak[r];
        vo[(size_t)(r0 + r) * KVN + t] = av[r];
    }
}

// ---- flash attention: 256 thr = 2 key-subsets x (64 queries x 2 heads) --------
// Each subset processes interleaved 64-key tiles in its own LDS K/V pair;
// subsets merge (m,l,acc) once at the end via LDS (exact online-softmax algebra).
extern "C" __global__ void __launch_bounds__(256)
mla_attn(const bf16* __restrict__ q, const float* __restrict__ kk,
         const float* __restrict__ vv, bf16* __restrict__ ao) {
    __shared__ float lds[4][64][KPAD];        // 53.2 KB: [2*sub]=K, [2*sub+1]=V
    const int qt = (int)gridDim.x - 1 - (int)blockIdx.x;  // heavy tiles first
    const int g  = blockIdx.y;
    const int b  = blockIdx.z;
    const int t  = threadIdx.x;               // 0..255
    const int sub = t >> 7;                   // key subset
    const int ts  = t & 127;
    const int lq  = ts & 63;                  // query within tile
    const int hh  = ts >> 6;                  // head within latent group
    const int i   = qt * 64 + lq;
    const int h   = g * 2 + hh;
    const float scale = 0.14433756729740643f; // 1/sqrt(48)

    float (*ks)[KPAD] = lds[2 * sub];
    float (*vs)[KPAD] = lds[2 * sub + 1];

    float qv[HDq];
    const bf16* qr = q + (size_t)(b * Tq + i) * QN + h * HDq;
    #pragma unroll
    for (int d = 0; d < HDq; ++d) qv[d] = b2f(qr[d]) * scale;

    float m = -1e30f, l = 0.f;
    float acc[HDq];
    #pragma unroll
    for (int d = 0; d < HDq; ++d) acc[d] = 0.f;

    const float* kbase = kk + (size_t)b * Tq * KVN + g * HDq;
    const float* vbase = vv + (size_t)b * Tq * KVN + g * HDq;
    const int nt = qt + 1;                    // number of 64-key tiles
    const int nIter = (nt + 1) >> 1;

    for (int it = 0; it < nIter; ++it) {
        const int tile = 2 * it + sub;        // interleaved: sub0 even, sub1 odd
        const bool valid = tile < nt;
        if (valid) {
            const int r = ts & 63;
            const float* src = (ts < 64) ? (kbase + (size_t)(tile * 64 + r) * KVN)
                                         : (vbase + (size_t)(tile * 64 + r) * KVN);
            float* dst = (ts < 64) ? &ks[r][0] : &vs[r][0];
            #pragma unroll
            for (int c = 0; c < 12; ++c) {
                const float4 v4 = *(const float4*)(src + 4 * c);
                dst[4 * c + 0] = v4.x; dst[4 * c + 1] = v4.y;
                dst[4 * c + 2] = v4.z; dst[4 * c + 3] = v4.w;
            }
        }
        __syncthreads();
        if (valid) {
            const int j0 = tile * 64;
            if (tile == qt) {                 // causal boundary tile
                for (int jj = 0; jj < 64; ++jj) {
                    if (j0 + jj <= i) {
                        const float4* kr = (const float4*)&ks[jj][0];
                        float s0 = 0.f, s1 = 0.f, s2 = 0.f, s3 = 0.f;
                        #pragma unroll
                        for (int c = 0; c < 12; ++c) {
                            const float4 k4 = kr[c];
                            s0 = fmaf(qv[4 * c + 0], k4.x, s0);
                            s1 = fmaf(qv[4 * c + 1], k4.y, s1);
                            s2 = fmaf(qv[4 * c + 2], k4.z, s2);
                            s3 = fmaf(qv[4 * c + 3], k4.w, s3);
                        }
                        const float s = (s0 + s1) + (s2 + s3);
                        const float nm = fmaxf(m, s);
                        const float f = __expf(m - nm);
                        const float p = __expf(s - nm);
                        l = l * f + p;
                        const float4* vr = (const float4*)&vs[jj][0];
                        #pragma unroll
                        for (int c = 0; c < 12; ++c) {
                            const float4 v4 = vr[c];
                            acc[4 * c + 0] = fmaf(acc[4 * c + 0], f, p * v4.x);
                            acc[4 * c + 1] = fmaf(acc[4 * c + 1], f, p * v4.y);
                            acc[4 * c + 2] = fmaf(acc[4 * c + 2], f, p * v4.z);
                            acc[4 * c + 3] = fmaf(acc[4 * c + 3], f, p * v4.w);
                        }
                        m = nm;
                    }
                }
            } else {                          // full tile, no guard
                for (int jj = 0; jj < 64; ++jj) {
                    const float4* kr = (const float4*)&ks[jj][0];
                    float s0 = 0.f, s1 = 0.f, s2 = 0.f, s3 = 0.f;
                    #pragma unroll
                    for (int c = 0; c < 12; ++c) {
                        const float4 k4 = kr[c];
                        s0 = fmaf(qv[4 * c + 0], k4.x, s0);
                        s1 = fmaf(qv[4 * c + 1], k4.y, s1);
                        s2 = fmaf(qv[4 * c + 2], k4.z, s2);
                        s3 = fmaf(qv[4 * c + 3], k4.w, s3);
                    }
                    const float s = (s0 + s1) + (s2 + s3);
                    const float nm = fmaxf(m, s);
                    const float f = __expf(m - nm);
                    const float p = __expf(s - nm);
                    l = l * f + p;
                    const float4* vr = (const float4*)&vs[jj][0];
                    #pragma unroll
                    for (int c = 0; c < 12; ++c) {
                        const float4 v4 = vr[c];
                        acc[4 * c + 0] = fmaf(acc[4 * c + 0], f, p * v4.x);
                        acc[4 * c + 1] = fmaf(acc[4 * c + 1], f, p * v4.y);
                        acc[4 * c + 2] = fmaf(acc[4 * c + 2], f, p * v4.z);
                        acc[4 * c + 3] = fmaf(acc[4 * c + 3], f, p * v4.w);
                    }
                    m = nm;
                }
            }
        }
        __syncthreads();
    }

    // merge the two subsets: sub1 publishes (m,l,acc) via LDS (stride 51 = odd,
    // 2-way bank aliasing only), sub0 combines and writes output.
    float* sc = &lds[0][0][0];                // 13312 floats available, need 6528
    if (sub == 1) {
        float* row = sc + ts * 51;
        row[0] = m; row[1] = l;
        #pragma unroll
        for (int d = 0; d < HDq; ++d) row[2 + d] = acc[d];
    }
    __syncthreads();
    if (sub == 0) {
        const float* row = sc + ts * 51;
        const float mB = row[0], lB = row[1];
        const float M = fmaxf(m, mB);
        const float fA = __expf(m - M);
        const float fB = __expf(mB - M);
        const float inv = 1.0f / (l * fA + lB * fB);
        bf16* orow = ao + (size_t)(b * Tq + i) * QN + h * HDq;
        #pragma unroll
        for (int d = 0; d < HDq; ++d)
            orow[d] = __float2bfloat16((acc[d] * fA + row[2 + d] * fB) * inv);
    }
}

// ---- out = ao(bf16) @ Wo : [4096,768]x[768,2048] -> fp32, 8 rows/block --------
extern "C" __global__ void __launch_bounds__(256)
mla_oproj(const bf16* __restrict__ ao, const float* __restrict__ Wo, float* __restrict__ out) {
    __shared__ float as[8][QN];               // 24 KB
    const int r0 = blockIdx.x * 8;
    const int t = threadIdx.x;
    #pragma unroll
    for (int r = 0; r < 8; ++r)
        for (int c = t; c < QN; c += 256)
            as[r][c] = b2f(ao[(size_t)(r0 + r) * QN + c]);
    __syncthreads();
    float acc[8][8];
    #pragma unroll
    for (int r = 0; r < 8; ++r)
        #pragma unroll
        for (int c = 0; c < 8; ++c) acc[r][c] = 0.f;
    for (int k = 0; k < QN; ++k) {
        const float* wr = Wo + (size_t)k * Dq;
        float w[8];
        #pragma unroll
        for (int c = 0; c < 8; ++c) w[c] = wr[t + 256 * c];
        #pragma unroll
        for (int r = 0; r < 8; ++r) {
            const float a = as[r][k];
            #pragma unroll
            for (int c = 0; c < 8; ++c) acc[r][c] = fmaf(a, w[c], acc[r][c]);
        }
    }
    #pragma unroll
    for (int r = 0; r < 8; ++r) {
        float* orow = out + (size_t)(r0 + r) * Dq;
        #pragma unroll
        for (int c = 0; c < 8; ++c) orow[t + 256 * c] = acc[r][c];
    }
}

extern "C" void kernel_launch(void* const* d_in, const int* in_sizes, int n_in,
                              void* d_out, int out_size, void* d_ws, size_t ws_size,
                              hipStream_t stream) {
    const float* x   = (const float*)d_in[0];
    // d_in[1]: causal mask — static tril, applied analytically in mla_attn
    const float* Wq  = (const float*)d_in[2];
    const float* Wkv = (const float*)d_in[3];
    const float* wn  = (const float*)d_in[4];
    const float* Wk  = (const float*)d_in[5];
    const float* Wv  = (const float*)d_in[6];
    const float* Wo  = (const float*)d_in[7];
    float* out = (float*)d_out;

    const int M = Bq * Tq;                          // 4096 rows
    // q bf16 parked in d_out (6.29 MB of 16.8 MB): dead before mla_oproj overwrites.
    bf16* qws = (bf16*)d_out;
    // ws: lat fp32 4.19MB | k fp32 6.29MB | v fp32 6.29MB | ao bf16 6.29MB = 23.07MB (proven)
    float* lat = (float*)d_ws;
    float* kws = lat + (size_t)M * LATq;
    float* vws = kws + (size_t)M * KVN;
    bf16*  aob = (bf16*)(vws + (size_t)M * KVN);

    mla_qproj <<<M / 8, 256, 0, stream>>>(x, Wq, qws);
    mla_kvlat <<<M / 8, 256, 0, stream>>>(x, Wkv, wn, lat);
    mla_kvproj<<<M / 8, 384, 0, stream>>>(lat, Wk, Wv, kws, vws);
    mla_attn  <<<dim3(Tq / 64, NLHq, Bq), 256, 0, stream>>>(qws, kws, vws, aob);
    mla_oproj <<<M / 8, 256, 0, stream>>>(aob, Wo, out);
}

// Round 8
// 1421.121 us; speedup vs baseline: 2.9929x; 1.2651x over previous
//
#include <hip/hip_runtime.h>
#include <hip/hip_bf16.h>

typedef __hip_bfloat16 bf16;

#define Bq   2
#define Tq   2048
#define Dq   2048
#define NHq  16
#define HDq  48
#define LATq 256
#define NLHq 8
#define QN   (NHq * HDq)    // 768
#define KVN  (NLHq * HDq)   // 384
#define KPAD 52             // LDS K/V row stride (floats): 16B-aligned
#define NROW ((size_t)Bq * NHq * Tq)   // 65536 partial rows

__device__ __forceinline__ float b2f(bf16 v) { return __bfloat162float(v); }

// ---- q = x @ Wq : [4096,2048]x[2048,768] -> bf16 (into d_out), 8 rows/block ----
extern "C" __global__ void __launch_bounds__(256)
mla_qproj(const float* __restrict__ x, const float* __restrict__ Wq, bf16* __restrict__ q) {
    __shared__ float xs[8][1024];            // 32 KB, k-chunked
    const int r0 = blockIdx.x * 8;
    const int t = threadIdx.x;
    float acc[8][3];
    #pragma unroll
    for (int r = 0; r < 8; ++r)
        #pragma unroll
        for (int c = 0; c < 3; ++c) acc[r][c] = 0.f;

    for (int kc = 0; kc < 2; ++kc) {
        __syncthreads();
        #pragma unroll
        for (int n = 0; n < 8; ++n) {
            const int idx4 = t + 256 * n;
            const int r = idx4 >> 8, c4 = idx4 & 255;
            *(float4*)&xs[r][c4 * 4] =
                *(const float4*)&x[(size_t)(r0 + r) * Dq + kc * 1024 + c4 * 4];
        }
        __syncthreads();
        for (int k = 0; k < 1024; ++k) {
            const float* wr = Wq + (size_t)(kc * 1024 + k) * QN;
            const float w0 = wr[t], w1 = wr[t + 256], w2 = wr[t + 512];
            #pragma unroll
            for (int r = 0; r < 8; ++r) {
                const float xv = xs[r][k];
                acc[r][0] = fmaf(xv, w0, acc[r][0]);
                acc[r][1] = fmaf(xv, w1, acc[r][1]);
                acc[r][2] = fmaf(xv, w2, acc[r][2]);
            }
        }
    }
    #pragma unroll
    for (int r = 0; r < 8; ++r) {
        bf16* qr = q + (size_t)(r0 + r) * QN;
        qr[t]       = __float2bfloat16(acc[r][0]);
        qr[t + 256] = __float2bfloat16(acc[r][1]);
        qr[t + 512] = __float2bfloat16(acc[r][2]);
    }
}

// ---- lat = rmsnorm(x @ Wkv) : [4096,2048]x[2048,256] -> fp32, 8 rows/block ----
extern "C" __global__ void __launch_bounds__(256)
mla_kvlat(const float* __restrict__ x, const float* __restrict__ Wkv,
          const float* __restrict__ wn, float* __restrict__ lat) {
    __shared__ float xs[8][1024];            // 32 KB, k-chunked
    __shared__ float red[8][256];            // 8 KB
    const int r0 = blockIdx.x * 8;
    const int t = threadIdx.x;
    float acc[8];
    #pragma unroll
    for (int r = 0; r < 8; ++r) acc[r] = 0.f;

    for (int kc = 0; kc < 2; ++kc) {
        __syncthreads();
        #pragma unroll
        for (int n = 0; n < 8; ++n) {
            const int idx4 = t + 256 * n;
            const int r = idx4 >> 8, c4 = idx4 & 255;
            *(float4*)&xs[r][c4 * 4] =
                *(const float4*)&x[(size_t)(r0 + r) * Dq + kc * 1024 + c4 * 4];
        }
        __syncthreads();
        for (int k = 0; k < 1024; ++k) {
            const float w = Wkv[(size_t)(kc * 1024 + k) * LATq + t];
            #pragma unroll
            for (int r = 0; r < 8; ++r) acc[r] = fmaf(xs[r][k], w, acc[r]);
        }
    }
    #pragma unroll
    for (int r = 0; r < 8; ++r) red[r][t] = acc[r] * acc[r];
    __syncthreads();
    for (int s = 128; s > 0; s >>= 1) {
        if (t < s) {
            #pragma unroll
            for (int r = 0; r < 8; ++r) red[r][t] += red[r][t + s];
        }
        __syncthreads();
    }
    const float w = wn[t];
    #pragma unroll
    for (int r = 0; r < 8; ++r) {
        const float rr = rsqrtf(red[r][0] * (1.0f / LATq) + 1e-5f);
        lat[(size_t)(r0 + r) * LATq + t] = acc[r] * rr * w;
    }
}

// ---- k,v = lat @ Wk / lat @ Wv : [4096,256]x[256,384] -> bf16, 8 rows/block ---
extern "C" __global__ void __launch_bounds__(384)
mla_kvproj(const float* __restrict__ lat, const float* __restrict__ Wk,
           const float* __restrict__ Wv, bf16* __restrict__ ko, bf16* __restrict__ vo) {
    __shared__ float ls[8][LATq];             // 8 KB
    const int r0 = blockIdx.x * 8;
    const int t = threadIdx.x;                // 0..383
    for (int idx = t; idx < 8 * LATq; idx += 384) {
        const int r = idx >> 8, c = idx & 255;
        ls[r][c] = lat[(size_t)(r0 + r) * LATq + c];
    }
    __syncthreads();
    float ak[8], av[8];
    #pragma unroll
    for (int r = 0; r < 8; ++r) { ak[r] = 0.f; av[r] = 0.f; }
    for (int k = 0; k < LATq; ++k) {
        const float wk = Wk[(size_t)k * KVN + t];
        const float wv = Wv[(size_t)k * KVN + t];
        #pragma unroll
        for (int r = 0; r < 8; ++r) {
            const float lv = ls[r][k];
            ak[r] = fmaf(lv, wk, ak[r]);
            av[r] = fmaf(lv, wv, av[r]);
        }
    }
    #pragma unroll
    for (int r = 0; r < 8; ++r) {
        ko[(size_t)(r0 + r) * KVN + t] = __float2bfloat16(ak[r]);
        vo[(size_t)(r0 + r) * KVN + t] = __float2bfloat16(av[r]);
    }
}

__device__ __forceinline__ void unpack8(uint4 u, float* dst) {
    float4 a, b;
    a.x = __uint_as_float(u.x << 16); a.y = __uint_as_float(u.x & 0xFFFF0000u);
    a.z = __uint_as_float(u.y << 16); a.w = __uint_as_float(u.y & 0xFFFF0000u);
    b.x = __uint_as_float(u.z << 16); b.y = __uint_as_float(u.z & 0xFFFF0000u);
    b.z = __uint_as_float(u.w << 16); b.w = __uint_as_float(u.w & 0xFFFF0000u);
    *(float4*)&dst[0] = a;
    *(float4*)&dst[4] = b;
}

// ---- split-K flash attention -------------------------------------------------
// grid (qt=32, g=8, b*3+s=6); block 128 = 64 queries x 2 heads.
// Split s handles key tiles [s*nt/3, (s+1)*nt/3), nt = qt+1. Emits unnormalized
// partial (m, l, acc[48]) per (b,h,i) row; mla_merge combines the 3 splits.
extern "C" __global__ void __launch_bounds__(128)
mla_attn(const bf16* __restrict__ q, const bf16* __restrict__ kk,
         const bf16* __restrict__ vv, bf16* __restrict__ acc0,
         bf16* __restrict__ acc1, bf16* __restrict__ acc2,
         float2* __restrict__ mlp) {
    __shared__ float ks[64][KPAD];            // 13.3 KB
    __shared__ float vs[64][KPAD];            // 13.3 KB
    const int qt = blockIdx.x;
    const int g  = blockIdx.y;
    const int zz = blockIdx.z;
    const int b  = zz / 3;
    const int s  = zz % 3;
    const int t  = threadIdx.x;               // 0..127
    const int lq = t & 63;
    const int hh = t >> 6;
    const int i  = qt * 64 + lq;
    const int h  = g * 2 + hh;
    const int nt = qt + 1;
    const int lo = (s * nt) / 3;
    const int hi = ((s + 1) * nt) / 3;
    const float scale = 0.14433756729740643f; // 1/sqrt(48)

    float qv[HDq];
    const bf16* qr = q + (size_t)(b * Tq + i) * QN + h * HDq;
    #pragma unroll
    for (int d = 0; d < HDq; ++d) qv[d] = b2f(qr[d]) * scale;

    float m = -1e30f, l = 0.f;
    float acc[HDq];
    #pragma unroll
    for (int d = 0; d < HDq; ++d) acc[d] = 0.f;

    const bf16* kb = kk + (size_t)b * Tq * KVN + g * HDq;
    const bf16* vb = vv + (size_t)b * Tq * KVN + g * HDq;

    for (int tl = lo; tl < hi; ++tl) {
        __syncthreads();
        // stage tile tl: 64 rows x 48 bf16 for K and V = 2x384 16B-chunks, 6/thread
        // NOTE: 384 is not a power of two — use subtraction, NOT `& 383` (R7 bug).
        #pragma unroll
        for (int n = 0; n < 6; ++n) {
            const int task = t + 128 * n;
            const int rem = (task < 384) ? task : task - 384;
            const int row = rem / 6, c = rem - row * 6;
            const bf16* src = ((task < 384) ? kb : vb) + (size_t)(tl * 64 + row) * KVN + c * 8;
            float* dst = ((task < 384) ? &ks[row][c * 8] : &vs[row][c * 8]);
            unpack8(*(const uint4*)src, dst);
        }
        __syncthreads();

        const int j0 = tl * 64;
        const bool bdry = (tl == qt);
        for (int jg = 0; jg < 16; ++jg) {
            float sc[4];
            #pragma unroll
            for (int u = 0; u < 4; ++u) {
                const float4* kr = (const float4*)&ks[jg * 4 + u][0];
                float s0 = 0.f, s1 = 0.f, s2 = 0.f, s3 = 0.f;
                #pragma unroll
                for (int c = 0; c < 12; ++c) {
                    const float4 k4 = kr[c];
                    s0 = fmaf(qv[4 * c + 0], k4.x, s0);
                    s1 = fmaf(qv[4 * c + 1], k4.y, s1);
                    s2 = fmaf(qv[4 * c + 2], k4.z, s2);
                    s3 = fmaf(qv[4 * c + 3], k4.w, s3);
                }
                const float sv = (s0 + s1) + (s2 + s3);
                sc[u] = (bdry && (j0 + jg * 4 + u > i)) ? -1e30f : sv;
            }
            const float nm = fmaxf(fmaxf(fmaxf(sc[0], sc[1]), fmaxf(sc[2], sc[3])), m);
            const float f  = __expf(m - nm);
            const float p0 = __expf(sc[0] - nm);
            const float p1 = __expf(sc[1] - nm);
            const float p2 = __expf(sc[2] - nm);
            const float p3 = __expf(sc[3] - nm);
            l = l * f + ((p0 + p1) + (p2 + p3));
            m = nm;
            const float4* v0 = (const float4*)&vs[jg * 4 + 0][0];
            const float4* v1 = (const float4*)&vs[jg * 4 + 1][0];
            const float4* v2 = (const float4*)&vs[jg * 4 + 2][0];
            const float4* v3 = (const float4*)&vs[jg * 4 + 3][0];
            #pragma unroll
            for (int c = 0; c < 12; ++c) {
                const float4 a0 = v0[c], a1 = v1[c], a2 = v2[c], a3 = v3[c];
                acc[4*c+0] = fmaf(p3, a3.x, fmaf(p2, a2.x, fmaf(p1, a1.x, fmaf(p0, a0.x, acc[4*c+0] * f))));
                acc[4*c+1] = fmaf(p3, a3.y, fmaf(p2, a2.y, fmaf(p1, a1.y, fmaf(p0, a0.y, acc[4*c+1] * f))));
                acc[4*c+2] = fmaf(p3, a3.z, fmaf(p2, a2.z, fmaf(p1, a1.z, fmaf(p0, a0.z, acc[4*c+2] * f))));
                acc[4*c+3] = fmaf(p3, a3.w, fmaf(p2, a2.w, fmaf(p1, a1.w, fmaf(p0, a0.w, acc[4*c+3] * f))));
            }
        }
    }

    // publish partial (empty ranges publish m=-1e30, l=0, acc=0)
    const size_t row = ((size_t)(b * NHq + h)) * Tq + i;
    bf16* prow = (s == 0 ? acc0 : (s == 1 ? acc1 : acc2)) + row * HDq;
    #pragma unroll
    for (int d = 0; d < HDq; ++d) prow[d] = __float2bfloat16(acc[d]);
    mlp[(size_t)s * NROW + row] = make_float2(m, l);
}

// ---- merge 3 split-K partials -> ao bf16 (standard [b,i,h*48+d] layout) -------
extern "C" __global__ void __launch_bounds__(256)
mla_merge(const bf16* __restrict__ acc0, const bf16* __restrict__ acc1,
          const bf16* __restrict__ acc2, const float2* __restrict__ mlp,
          bf16* __restrict__ ao) {
    const int r = blockIdx.x * 256 + threadIdx.x;   // 0..65535 = (b,h,i)
    const float2 ml0 = mlp[r];
    const float2 ml1 = mlp[NROW + r];
    const float2 ml2 = mlp[2 * NROW + r];
    const float M = fmaxf(ml0.x, fmaxf(ml1.x, ml2.x));
    const float f0 = __expf(ml0.x - M);
    const float f1 = __expf(ml1.x - M);
    const float f2 = __expf(ml2.x - M);
    const float inv = 1.0f / (ml0.y * f0 + ml1.y * f1 + ml2.y * f2);
    const int b = r >> 15;
    const int h = (r >> 11) & 15;
    const int i = r & 2047;
    bf16* orow = ao + (size_t)(b * Tq + i) * QN + h * HDq;
    const bf16* p0 = acc0 + (size_t)r * HDq;
    const bf16* p1 = acc1 + (size_t)r * HDq;
    const bf16* p2 = acc2 + (size_t)r * HDq;
    #pragma unroll
    for (int d = 0; d < HDq; ++d)
        orow[d] = __float2bfloat16((b2f(p0[d]) * f0 + b2f(p1[d]) * f1 + b2f(p2[d]) * f2) * inv);
}

// ---- out = ao(bf16) @ Wo : [4096,768]x[768,2048] -> fp32, 8 rows/block --------
extern "C" __global__ void __launch_bounds__(256)
mla_oproj(const bf16* __restrict__ ao, const float* __restrict__ Wo, float* __restrict__ out) {
    __shared__ float as[8][QN];               // 24 KB
    const int r0 = blockIdx.x * 8;
    const int t = threadIdx.x;
    #pragma unroll
    for (int r = 0; r < 8; ++r)
        for (int c = t; c < QN; c += 256)
            as[r][c] = b2f(ao[(size_t)(r0 + r) * QN + c]);
    __syncthreads();
    float acc[8][8];
    #pragma unroll
    for (int r = 0; r < 8; ++r)
        #pragma unroll
        for (int c = 0; c < 8; ++c) acc[r][c] = 0.f;
    for (int k = 0; k < QN; ++k) {
        const float* wr = Wo + (size_t)k * Dq;
        float w[8];
        #pragma unroll
        for (int c = 0; c < 8; ++c) w[c] = wr[t + 256 * c];
        #pragma unroll
        for (int r = 0; r < 8; ++r) {
            const float a = as[r][k];
            #pragma unroll
            for (int c = 0; c < 8; ++c) acc[r][c] = fmaf(a, w[c], acc[r][c]);
        }
    }
    #pragma unroll
    for (int r = 0; r < 8; ++r) {
        float* orow = out + (size_t)(r0 + r) * Dq;
        #pragma unroll
        for (int c = 0; c < 8; ++c) orow[t + 256 * c] = acc[r][c];
    }
}

extern "C" void kernel_launch(void* const* d_in, const int* in_sizes, int n_in,
                              void* d_out, int out_size, void* d_ws, size_t ws_size,
                              hipStream_t stream) {
    const float* x   = (const float*)d_in[0];
    // d_in[1]: causal mask — static tril, applied analytically in mla_attn
    const float* Wq  = (const float*)d_in[2];
    const float* Wkv = (const float*)d_in[3];
    const float* wn  = (const float*)d_in[4];
    const float* Wk  = (const float*)d_in[5];
    const float* Wv  = (const float*)d_in[6];
    const float* Wo  = (const float*)d_in[7];
    float* out = (float*)d_out;

    const int M = Bq * Tq;                          // 4096 rows
    // d_out is fp32 [4096,2048] = 33.55 MB. Layout until oproj overwrites it:
    //   [0      : 6.29M)  q bf16          (dead after attn)
    //   [6.29M  : 12.58M) acc0 bf16 partials
    //   [12.58M : 18.87M) acc1
    //   [18.87M : 25.17M) acc2
    //   [25.17M : 26.74M) ml float2 x 3 splits
    char* ob = (char*)d_out;
    const size_t PSZ = (size_t)M * QN * sizeof(bf16);   // 6291456
    bf16*   qws  = (bf16*)d_out;
    bf16*   acc0 = (bf16*)(ob + PSZ);
    bf16*   acc1 = (bf16*)(ob + 2 * PSZ);
    bf16*   acc2 = (bf16*)(ob + 3 * PSZ);
    float2* mlp  = (float2*)(ob + 4 * PSZ);
    // ws: k bf16 3.15M | v bf16 3.15M | ao bf16 6.29M = 12.6 MB.
    // lat fp32 (4.19M) overlays the ao region: dead before merge writes ao.
    bf16*  kws = (bf16*)d_ws;
    bf16*  vws = kws + (size_t)M * KVN;
    bf16*  aob = vws + (size_t)M * KVN;
    float* lat = (float*)aob;

    mla_qproj <<<M / 8, 256, 0, stream>>>(x, Wq, qws);
    mla_kvlat <<<M / 8, 256, 0, stream>>>(x, Wkv, wn, lat);
    mla_kvproj<<<M / 8, 384, 0, stream>>>(lat, Wk, Wv, kws, vws);
    mla_attn  <<<dim3(Tq / 64, NLHq, Bq * 3), 128, 0, stream>>>(qws, kws, vws,
                                                                acc0, acc1, acc2, mlp);
    mla_merge <<<(int)(NROW / 256), 256, 0, stream>>>(acc0, acc1, acc2, mlp, aob);
    mla_oproj <<<M / 8, 256, 0, stream>>>(aob, Wo, out);
}

// Round 9
// 894.233 us; speedup vs baseline: 4.7563x; 1.5892x over previous
//
#include <hip/hip_runtime.h>
#include <hip/hip_bf16.h>

typedef __hip_bfloat16 bf16;
typedef __attribute__((ext_vector_type(8))) short short8;
typedef __attribute__((ext_vector_type(4))) float f32x4;

#define Bq   2
#define Tq   2048
#define Dq   2048
#define NHq  16
#define HDq  48
#define LATq 256
#define NLHq 8
#define QN   (NHq * HDq)    // 768
#define KVN  (NLHq * HDq)   // 384
#define KPAD 52             // attn LDS K/V row stride (floats)
#define NCH  80             // key-chunks per (b,g): sum over qt of ceil((qt+1)/8)
#define NPR  ((size_t)16 * NCH * 128)   // 163840 partial rows

__device__ __forceinline__ float b2f(bf16 v) { return __bfloat162float(v); }
__device__ __forceinline__ unsigned short f2u(float x) {
    __hip_bfloat16 h = __float2bfloat16(x);
    return *reinterpret_cast<unsigned short*>(&h);
}

// ==== MFMA GEMM: q = x @ Wq, [4096,2048]fp32 x [2048,768]fp32 -> bf16 ==========
// block 256 thr = 4 waves (2x2), tile 64x64, BK=32. A_lds[m][k] s40; B_lds[n][k]
// s40 with 16B-chunk XOR swizzle (chunk ^= (n>>2)&3) for conflict-light staging.
extern "C" __global__ void __launch_bounds__(256)
mla_qproj(const float* __restrict__ A, const float* __restrict__ B, bf16* __restrict__ C) {
    __shared__ short As[64 * 40];
    __shared__ short Bs[64 * 40];
    const int t  = threadIdx.x;
    const int m0 = blockIdx.x * 64;
    const int n0 = blockIdx.y * 64;
    const int w  = t >> 6;
    const int wm = (w & 1) * 32;
    const int wn = (w >> 1) * 32;
    const int l  = t & 63;
    const int lr = l & 15;
    const int quad = l >> 4;

    f32x4 acc[2][2];
    #pragma unroll
    for (int mi = 0; mi < 2; ++mi)
        #pragma unroll
        for (int ni = 0; ni < 2; ++ni) acc[mi][ni] = (f32x4){0.f, 0.f, 0.f, 0.f};

    int aoff[2], boff[2];
    #pragma unroll
    for (int mi = 0; mi < 2; ++mi) aoff[mi] = (wm + mi * 16 + lr) * 40 + quad * 8;
    #pragma unroll
    for (int ni = 0; ni < 2; ++ni) {
        const int n = wn + ni * 16 + lr;
        boff[ni] = n * 40 + (quad ^ ((n >> 2) & 3)) * 8;
    }

    for (int kt = 0; kt < Dq / 32; ++kt) {
        #pragma unroll
        for (int it = 0; it < 2; ++it) {              // A-tile 64x32: 512 float4
            const int idx = t + 256 * it;
            const int m = idx >> 3, k4 = idx & 7;
            const float4 a4 = *(const float4*)&A[(size_t)(m0 + m) * Dq + kt * 32 + k4 * 4];
            const unsigned u0 = f2u(a4.x) | ((unsigned)f2u(a4.y) << 16);
            const unsigned u1 = f2u(a4.z) | ((unsigned)f2u(a4.w) << 16);
            *(uint2*)&As[m * 40 + k4 * 4] = make_uint2(u0, u1);
        }
        #pragma unroll
        for (int it = 0; it < 2; ++it) {              // B-tile 32x64 transposed
            const int idx = t + 256 * it;
            const int k = idx >> 4, n4 = idx & 15;
            const float4 b4 = *(const float4*)&B[(size_t)(kt * 32 + k) * QN + n0 + n4 * 4];
            const float bb[4] = {b4.x, b4.y, b4.z, b4.w};
            #pragma unroll
            for (int j = 0; j < 4; ++j) {
                const int n = n4 * 4 + j;
                const int ch = (k >> 3) ^ ((n >> 2) & 3);
                Bs[n * 40 + ch * 8 + (k & 7)] = (short)f2u(bb[j]);
            }
        }
        __syncthreads();
        short8 af[2], bfr[2];
        #pragma unroll
        for (int mi = 0; mi < 2; ++mi) af[mi] = *(const short8*)&As[aoff[mi]];
        #pragma unroll
        for (int ni = 0; ni < 2; ++ni) bfr[ni] = *(const short8*)&Bs[boff[ni]];
        #pragma unroll
        for (int mi = 0; mi < 2; ++mi)
            #pragma unroll
            for (int ni = 0; ni < 2; ++ni)
                acc[mi][ni] = __builtin_amdgcn_mfma_f32_16x16x32_bf16(af[mi], bfr[ni], acc[mi][ni], 0, 0, 0);
        __syncthreads();
    }
    #pragma unroll
    for (int mi = 0; mi < 2; ++mi)
        #pragma unroll
        for (int ni = 0; ni < 2; ++ni) {
            const int col = n0 + wn + ni * 16 + lr;
            #pragma unroll
            for (int r = 0; r < 4; ++r) {
                const int row = m0 + wm + mi * 16 + quad * 4 + r;
                C[(size_t)row * QN + col] = __float2bfloat16(acc[mi][ni][r]);
            }
        }
}

// ==== MFMA GEMM: out = ao @ Wo, [4096,768]bf16 x [768,2048]fp32 -> fp32 ========
extern "C" __global__ void __launch_bounds__(256)
mla_oproj(const bf16* __restrict__ A, const float* __restrict__ B, float* __restrict__ C) {
    __shared__ short As[64 * 40];
    __shared__ short Bs[64 * 40];
    const int t  = threadIdx.x;
    const int m0 = blockIdx.x * 64;
    const int n0 = blockIdx.y * 64;
    const int w  = t >> 6;
    const int wm = (w & 1) * 32;
    const int wn = (w >> 1) * 32;
    const int l  = t & 63;
    const int lr = l & 15;
    const int quad = l >> 4;

    f32x4 acc[2][2];
    #pragma unroll
    for (int mi = 0; mi < 2; ++mi)
        #pragma unroll
        for (int ni = 0; ni < 2; ++ni) acc[mi][ni] = (f32x4){0.f, 0.f, 0.f, 0.f};

    int aoff[2], boff[2];
    #pragma unroll
    for (int mi = 0; mi < 2; ++mi) aoff[mi] = (wm + mi * 16 + lr) * 40 + quad * 8;
    #pragma unroll
    for (int ni = 0; ni < 2; ++ni) {
        const int n = wn + ni * 16 + lr;
        boff[ni] = n * 40 + (quad ^ ((n >> 2) & 3)) * 8;
    }

    for (int kt = 0; kt < QN / 32; ++kt) {
        {                                             // A-tile 64x32 bf16: 256 uint4
            const int m = t >> 2, k8 = t & 3;
            *(uint4*)&As[m * 40 + k8 * 8] =
                *(const uint4*)&A[(size_t)(m0 + m) * QN + kt * 32 + k8 * 8];
        }
        #pragma unroll
        for (int it = 0; it < 2; ++it) {              // B-tile 32x64 transposed
            const int idx = t + 256 * it;
            const int k = idx >> 4, n4 = idx & 15;
            const float4 b4 = *(const float4*)&B[(size_t)(kt * 32 + k) * Dq + n0 + n4 * 4];
            const float bb[4] = {b4.x, b4.y, b4.z, b4.w};
            #pragma unroll
            for (int j = 0; j < 4; ++j) {
                const int n = n4 * 4 + j;
                const int ch = (k >> 3) ^ ((n >> 2) & 3);
                Bs[n * 40 + ch * 8 + (k & 7)] = (short)f2u(bb[j]);
            }
        }
        __syncthreads();
        short8 af[2], bfr[2];
        #pragma unroll
        for (int mi = 0; mi < 2; ++mi) af[mi] = *(const short8*)&As[aoff[mi]];
        #pragma unroll
        for (int ni = 0; ni < 2; ++ni) bfr[ni] = *(const short8*)&Bs[boff[ni]];
        #pragma unroll
        for (int mi = 0; mi < 2; ++mi)
            #pragma unroll
            for (int ni = 0; ni < 2; ++ni)
                acc[mi][ni] = __builtin_amdgcn_mfma_f32_16x16x32_bf16(af[mi], bfr[ni], acc[mi][ni], 0, 0, 0);
        __syncthreads();
    }
    #pragma unroll
    for (int mi = 0; mi < 2; ++mi)
        #pragma unroll
        for (int ni = 0; ni < 2; ++ni) {
            const int col = n0 + wn + ni * 16 + lr;
            #pragma unroll
            for (int r = 0; r < 4; ++r) {
                const int row = m0 + wm + mi * 16 + quad * 4 + r;
                C[(size_t)row * Dq + col] = acc[mi][ni][r];
            }
        }
}

// ---- lat = rmsnorm(x @ Wkv) : [4096,2048]x[2048,256] -> fp32, 8 rows/block ----
extern "C" __global__ void __launch_bounds__(256)
mla_kvlat(const float* __restrict__ x, const float* __restrict__ Wkv,
          const float* __restrict__ wn, float* __restrict__ lat) {
    __shared__ float xs[8][1024];
    __shared__ float red[8][256];
    const int r0 = blockIdx.x * 8;
    const int t = threadIdx.x;
    float acc[8];
    #pragma unroll
    for (int r = 0; r < 8; ++r) acc[r] = 0.f;

    for (int kc = 0; kc < 2; ++kc) {
        __syncthreads();
        #pragma unroll
        for (int n = 0; n < 8; ++n) {
            const int idx4 = t + 256 * n;
            const int r = idx4 >> 8, c4 = idx4 & 255;
            *(float4*)&xs[r][c4 * 4] =
                *(const float4*)&x[(size_t)(r0 + r) * Dq + kc * 1024 + c4 * 4];
        }
        __syncthreads();
        for (int k = 0; k < 1024; ++k) {
            const float w = Wkv[(size_t)(kc * 1024 + k) * LATq + t];
            #pragma unroll
            for (int r = 0; r < 8; ++r) acc[r] = fmaf(xs[r][k], w, acc[r]);
        }
    }
    #pragma unroll
    for (int r = 0; r < 8; ++r) red[r][t] = acc[r] * acc[r];
    __syncthreads();
    for (int s = 128; s > 0; s >>= 1) {
        if (t < s) {
            #pragma unroll
            for (int r = 0; r < 8; ++r) red[r][t] += red[r][t + s];
        }
        __syncthreads();
    }
    const float w = wn[t];
    #pragma unroll
    for (int r = 0; r < 8; ++r) {
        const float rr = rsqrtf(red[r][0] * (1.0f / LATq) + 1e-5f);
        lat[(size_t)(r0 + r) * LATq + t] = acc[r] * rr * w;
    }
}

// ---- k,v = lat @ Wk / lat @ Wv : [4096,256]x[256,384] -> bf16, 8 rows/block ---
extern "C" __global__ void __launch_bounds__(384)
mla_kvproj(const float* __restrict__ lat, const float* __restrict__ Wk,
           const float* __restrict__ Wv, bf16* __restrict__ ko, bf16* __restrict__ vo) {
    __shared__ float ls[8][LATq];
    const int r0 = blockIdx.x * 8;
    const int t = threadIdx.x;
    for (int idx = t; idx < 8 * LATq; idx += 384) {
        const int r = idx >> 8, c = idx & 255;
        ls[r][c] = lat[(size_t)(r0 + r) * LATq + c];
    }
    __syncthreads();
    float ak[8], av[8];
    #pragma unroll
    for (int r = 0; r < 8; ++r) { ak[r] = 0.f; av[r] = 0.f; }
    for (int k = 0; k < LATq; ++k) {
        const float wk = Wk[(size_t)k * KVN + t];
        const float wv = Wv[(size_t)k * KVN + t];
        #pragma unroll
        for (int r = 0; r < 8; ++r) {
            const float lv = ls[r][k];
            ak[r] = fmaf(lv, wk, ak[r]);
            av[r] = fmaf(lv, wv, av[r]);
        }
    }
    #pragma unroll
    for (int r = 0; r < 8; ++r) {
        ko[(size_t)(r0 + r) * KVN + t] = __float2bfloat16(ak[r]);
        vo[(size_t)(r0 + r) * KVN + t] = __float2bfloat16(av[r]);
    }
}

__device__ __forceinline__ void unpack8(uint4 u, float* dst) {
    float4 a, b;
    a.x = __uint_as_float(u.x << 16); a.y = __uint_as_float(u.x & 0xFFFF0000u);
    a.z = __uint_as_float(u.y << 16); a.w = __uint_as_float(u.y & 0xFFFF0000u);
    b.x = __uint_as_float(u.z << 16); b.y = __uint_as_float(u.z & 0xFFFF0000u);
    b.z = __uint_as_float(u.w << 16); b.w = __uint_as_float(u.w & 0xFFFF0000u);
    *(float4*)&dst[0] = a;
    *(float4*)&dst[4] = b;
}

// ---- chunked flash attention: uniform 8-tile chunks, grid (80, 8, 2) ----------
// chunk c (per b,g) -> (qt, s): qt-group a has (a+1) chunks per qt for qt in
// [8a, 8a+7]; chunk covers key tiles [8s, min(8s+8, qt+1)). One partial
// (m,l,acc48) per (chunk, q, h) row, merged by mla_merge.
extern "C" __global__ void __launch_bounds__(128)
mla_attn(const bf16* __restrict__ q, const bf16* __restrict__ kk,
         const bf16* __restrict__ vv, bf16* __restrict__ accp,
         float2* __restrict__ mlp) {
    __shared__ float ks[64][KPAD];
    __shared__ float vs[64][KPAD];
    const int c  = (NCH - 1) - (int)blockIdx.x;   // heavy chunks first
    const int g  = blockIdx.y;
    const int b  = blockIdx.z;
    const int t  = threadIdx.x;
    const int lq = t & 63;
    const int hh = t >> 6;
    const int a  = (c < 8) ? 0 : (c < 24) ? 1 : (c < 48) ? 2 : 3;
    const int rr = c - 4 * a * (a + 1);
    const int per = a + 1;
    const int qt = 8 * a + rr / per;
    const int s  = rr - (rr / per) * per;
    const int nt = qt + 1;
    const int lo = s * 8;
    const int hi = (lo + 8 < nt) ? lo + 8 : nt;
    const int i  = qt * 64 + lq;
    const int h  = g * 2 + hh;
    const float scale = 0.14433756729740643f;     // 1/sqrt(48)

    float qv[HDq];
    const bf16* qr = q + (size_t)(b * Tq + i) * QN + h * HDq;
    #pragma unroll
    for (int d = 0; d < HDq; ++d) qv[d] = b2f(qr[d]) * scale;

    float m = -1e30f, l = 0.f;
    float acc[HDq];
    #pragma unroll
    for (int d = 0; d < HDq; ++d) acc[d] = 0.f;

    const bf16* kb = kk + (size_t)b * Tq * KVN + g * HDq;
    const bf16* vb = vv + (size_t)b * Tq * KVN + g * HDq;

    for (int tl = lo; tl < hi; ++tl) {
        __syncthreads();
        #pragma unroll
        for (int n = 0; n < 6; ++n) {
            const int task = t + 128 * n;
            const int rem = (task < 384) ? task : task - 384;   // NOT &383 (R7 bug)
            const int row = rem / 6, cc = rem - row * 6;
            const bf16* src = ((task < 384) ? kb : vb) + (size_t)(tl * 64 + row) * KVN + cc * 8;
            float* dst = ((task < 384) ? &ks[row][cc * 8] : &vs[row][cc * 8]);
            unpack8(*(const uint4*)src, dst);
        }
        __syncthreads();

        const int j0 = tl * 64;
        const bool bdry = (tl == qt);
        for (int jg = 0; jg < 16; ++jg) {
            float sc[4];
            #pragma unroll
            for (int u = 0; u < 4; ++u) {
                const float4* kr = (const float4*)&ks[jg * 4 + u][0];
                float s0 = 0.f, s1 = 0.f, s2 = 0.f, s3 = 0.f;
                #pragma unroll
                for (int cc = 0; cc < 12; ++cc) {
                    const float4 k4 = kr[cc];
                    s0 = fmaf(qv[4 * cc + 0], k4.x, s0);
                    s1 = fmaf(qv[4 * cc + 1], k4.y, s1);
                    s2 = fmaf(qv[4 * cc + 2], k4.z, s2);
                    s3 = fmaf(qv[4 * cc + 3], k4.w, s3);
                }
                const float sv = (s0 + s1) + (s2 + s3);
                sc[u] = (bdry && (j0 + jg * 4 + u > i)) ? -1e30f : sv;
            }
            const float nm = fmaxf(fmaxf(fmaxf(sc[0], sc[1]), fmaxf(sc[2], sc[3])), m);
            const float f  = __expf(m - nm);
            const float p0 = __expf(sc[0] - nm);
            const float p1 = __expf(sc[1] - nm);
            const float p2 = __expf(sc[2] - nm);
            const float p3 = __expf(sc[3] - nm);
            l = l * f + ((p0 + p1) + (p2 + p3));
            m = nm;
            const float4* v0 = (const float4*)&vs[jg * 4 + 0][0];
            const float4* v1 = (const float4*)&vs[jg * 4 + 1][0];
            const float4* v2 = (const float4*)&vs[jg * 4 + 2][0];
            const float4* v3 = (const float4*)&vs[jg * 4 + 3][0];
            #pragma unroll
            for (int cc = 0; cc < 12; ++cc) {
                const float4 a0 = v0[cc], a1 = v1[cc], a2 = v2[cc], a3 = v3[cc];
                acc[4*cc+0] = fmaf(p3, a3.x, fmaf(p2, a2.x, fmaf(p1, a1.x, fmaf(p0, a0.x, acc[4*cc+0] * f))));
                acc[4*cc+1] = fmaf(p3, a3.y, fmaf(p2, a2.y, fmaf(p1, a1.y, fmaf(p0, a0.y, acc[4*cc+1] * f))));
                acc[4*cc+2] = fmaf(p3, a3.z, fmaf(p2, a2.z, fmaf(p1, a1.z, fmaf(p0, a0.z, acc[4*cc+2] * f))));
                acc[4*cc+3] = fmaf(p3, a3.w, fmaf(p2, a2.w, fmaf(p1, a1.w, fmaf(p0, a0.w, acc[4*cc+3] * f))));
            }
        }
    }

    const size_t pr = ((size_t)((b * 8 + g) * NCH + c)) * 128 + t;
    bf16* prow = accp + pr * HDq;
    #pragma unroll
    for (int d = 0; d < HDq; ++d) prow[d] = __float2bfloat16(acc[d]);
    mlp[pr] = make_float2(m, l);
}

// ---- merge <=4 chunk partials per (b,h,i) -> ao bf16 --------------------------
extern "C" __global__ void __launch_bounds__(256)
mla_merge(const bf16* __restrict__ accp, const float2* __restrict__ mlp,
          bf16* __restrict__ ao) {
    const int r = blockIdx.x * 256 + threadIdx.x;   // (b,h,i)
    const int b = r >> 15, h = (r >> 11) & 15, i = r & 2047;
    const int g = h >> 1, hh = h & 1;
    const int lq = i & 63, qt = i >> 6;
    const int A = qt >> 3, rem = qt & 7;
    const int cum = qt + 8 * (A * (A - 1) / 2) + A * rem;   // chunks before qt
    const int P = A + 1;                                     // ceil((qt+1)/8)
    const size_t base = ((size_t)((b * 8 + g) * NCH + cum)) * 128 + hh * 64 + lq;
    float m = -1e30f, l = 0.f;
    float o[HDq];
    #pragma unroll
    for (int d = 0; d < HDq; ++d) o[d] = 0.f;
    for (int p = 0; p < P; ++p) {
        const size_t pr = base + (size_t)p * 128;
        const float2 ml = mlp[pr];
        const float M = fmaxf(m, ml.x);
        const float f0 = __expf(m - M), f1 = __expf(ml.x - M);
        l = l * f0 + ml.y * f1;
        const bf16* pa = accp + pr * HDq;
        #pragma unroll
        for (int d = 0; d < HDq; ++d) o[d] = o[d] * f0 + b2f(pa[d]) * f1;
        m = M;
    }
    const float inv = 1.0f / l;
    bf16* orow = ao + (size_t)(b * Tq + i) * QN + h * HDq;
    #pragma unroll
    for (int d = 0; d < HDq; ++d) orow[d] = __float2bfloat16(o[d] * inv);
}

extern "C" void kernel_launch(void* const* d_in, const int* in_sizes, int n_in,
                              void* d_out, int out_size, void* d_ws, size_t ws_size,
                              hipStream_t stream) {
    const float* x   = (const float*)d_in[0];
    // d_in[1]: causal mask — static tril, applied analytically in mla_attn
    const float* Wq  = (const float*)d_in[2];
    const float* Wkv = (const float*)d_in[3];
    const float* wn  = (const float*)d_in[4];
    const float* Wk  = (const float*)d_in[5];
    const float* Wv  = (const float*)d_in[6];
    const float* Wo  = (const float*)d_in[7];
    float* out = (float*)d_out;

    const int M = Bq * Tq;                          // 4096
    // d_out (33.55 MB fp32) staging layout, fully dead before oproj rewrites:
    //   [0        : 6.29M)   q bf16
    //   [6.29M    : 22.02M)  accp bf16: 163840 rows x 48
    //   [22.02M   : 23.33M)  mlp float2: 163840
    char* ob = (char*)d_out;
    bf16*   qws  = (bf16*)d_out;
    bf16*   accp = (bf16*)(ob + 6291456);
    float2* mlp  = (float2*)(ob + 6291456 + NPR * HDq * sizeof(bf16));
    // ws: k bf16 3.15M | v bf16 3.15M | ao bf16 6.29M (lat fp32 overlays ao)
    bf16*  kws = (bf16*)d_ws;
    bf16*  vws = kws + (size_t)M * KVN;
    bf16*  aob = vws + (size_t)M * KVN;
    float* lat = (float*)aob;

    mla_qproj <<<dim3(M / 64, QN / 64), 256, 0, stream>>>(x, Wq, qws);
    mla_kvlat <<<M / 8, 256, 0, stream>>>(x, Wkv, wn, lat);
    mla_kvproj<<<M / 8, 384, 0, stream>>>(lat, Wk, Wv, kws, vws);
    mla_attn  <<<dim3(NCH, NLHq, Bq), 128, 0, stream>>>(qws, kws, vws, accp, mlp);
    mla_merge <<<(int)((size_t)Bq * NHq * Tq / 256), 256, 0, stream>>>(accp, mlp, aob);
    mla_oproj <<<dim3(M / 64, Dq / 64), 256, 0, stream>>>(aob, Wo, out);
}